// Round 2
// baseline (40044.724 us; speedup 1.0000x reference)
//
#include <hip/hip_runtime.h>
#include <cstddef>

#define BB 64
#define SS 512
#define HH 512
#define BH (BB * HH)                     // 32768 floats
#define HN_OFF ((size_t)BB * SS * HH)    // start of h_n in d_out

// ============================================================================
// Kernel 1: pre0[b][t][j] = sum_i x[b,t,i] * Wih0[j,i] + b0[j]
// pre0 lives in the OUTPUT region of d_out (safe: kernel2 reads pre0[b][t] at
// step t and overwrites out[b][t] at step t+1, same thread, one iter later).
// ============================================================================
__global__ __launch_bounds__(256) void pregemm_kernel(
    const float* __restrict__ x, const float* __restrict__ Wih0,
    const float* __restrict__ b0, float* __restrict__ pre0) {
  __shared__ float xs[32][68];   // [k][b], padded
  __shared__ float ws[32][68];   // [k][j], padded
  const int t   = blockIdx.y;
  const int jb  = blockIdx.x * 64;
  const int tid = threadIdx.x;
  const int tx = tid & 15, ty = tid >> 4;       // compute mapping: 4b x 4j tile
  const int lrow = tid >> 2, kc = tid & 3;      // staging mapping

  float acc[4][4] = {{0.f, 0.f, 0.f, 0.f}, {0.f, 0.f, 0.f, 0.f},
                     {0.f, 0.f, 0.f, 0.f}, {0.f, 0.f, 0.f, 0.f}};

  const float* xrow = x + ((size_t)lrow * SS + t) * HH;       // b = lrow
  const float* wrow = Wih0 + (size_t)(jb + lrow) * HH;        // j = jb+lrow

  for (int k0 = 0; k0 < HH; k0 += 32) {
    float4 xa = *(const float4*)(xrow + k0 + kc * 4);
    float4 xb = *(const float4*)(xrow + k0 + (kc + 4) * 4);
    float4 wa = *(const float4*)(wrow + k0 + kc * 4);
    float4 wb = *(const float4*)(wrow + k0 + (kc + 4) * 4);
    __syncthreads();   // previous compute done before overwriting LDS
    xs[kc * 4 + 0][lrow] = xa.x; xs[kc * 4 + 1][lrow] = xa.y;
    xs[kc * 4 + 2][lrow] = xa.z; xs[kc * 4 + 3][lrow] = xa.w;
    xs[(kc + 4) * 4 + 0][lrow] = xb.x; xs[(kc + 4) * 4 + 1][lrow] = xb.y;
    xs[(kc + 4) * 4 + 2][lrow] = xb.z; xs[(kc + 4) * 4 + 3][lrow] = xb.w;
    ws[kc * 4 + 0][lrow] = wa.x; ws[kc * 4 + 1][lrow] = wa.y;
    ws[kc * 4 + 2][lrow] = wa.z; ws[kc * 4 + 3][lrow] = wa.w;
    ws[(kc + 4) * 4 + 0][lrow] = wb.x; ws[(kc + 4) * 4 + 1][lrow] = wb.y;
    ws[(kc + 4) * 4 + 2][lrow] = wb.z; ws[(kc + 4) * 4 + 3][lrow] = wb.w;
    __syncthreads();
#pragma unroll
    for (int kk = 0; kk < 32; ++kk) {
      float4 av = *(const float4*)&xs[kk][tx * 4];
      float4 bv = *(const float4*)&ws[kk][ty * 4];
      float aa[4] = {av.x, av.y, av.z, av.w};
      float bb4[4] = {bv.x, bv.y, bv.z, bv.w};
#pragma unroll
      for (int p = 0; p < 4; ++p)
#pragma unroll
        for (int q = 0; q < 4; ++q) acc[p][q] += aa[p] * bb4[q];
    }
  }
  float4 bias = *(const float4*)(b0 + jb + ty * 4);
  float bb4[4] = {bias.x, bias.y, bias.z, bias.w};
#pragma unroll
  for (int p = 0; p < 4; ++p) {
    float4 o;
    o.x = acc[p][0] + bb4[0]; o.y = acc[p][1] + bb4[1];
    o.z = acc[p][2] + bb4[2]; o.w = acc[p][3] + bb4[3];
    *(float4*)(pre0 + ((size_t)(tx * 4 + p) * SS + t) * HH + jb + ty * 4) = o;
  }
}

// ============================================================================
// Kernel 2: persistent recurrent kernel, 256 WGs x 512 thr (8 waves, 2/SIMD).
// WG (bg = blk&7, jg = blk>>3) owns batches bg*8..+8 and outputs j = jg*16..+16.
// Weights (3 x 16 x 512 f32 = 96 KB) stay in LDS for the whole kernel.
// Per step: one 32-WG domain barrier. Layer1 lags one step: iter t computes
// h0(t) and h1(t-1); all three matvecs read only state staged at iter start.
// ============================================================================
__device__ __forceinline__ void mat_acc4(const float* __restrict__ W,
                                         const float* __restrict__ h,
                                         int jt, int kb, float acc[8][4]) {
  float4 wv[4];
#pragma unroll
  for (int jj = 0; jj < 4; ++jj)
    wv[jj] = *(const float4*)&W[(jt * 4 + jj) * 512 + kb];
#pragma unroll
  for (int bi = 0; bi < 8; ++bi) {
    float4 hv = *(const float4*)&h[bi * 512 + kb];
#pragma unroll
    for (int jj = 0; jj < 4; ++jj)
      acc[bi][jj] += hv.x * wv[jj].x + hv.y * wv[jj].y +
                     hv.z * wv[jj].z + hv.w * wv[jj].w;
  }
}

__device__ __forceinline__ void store_partial(float acc[8][4], float* red,
                                              int tid, int jt) {
  if (((tid >> 2) & 15) == 0) {          // lanes 0..3 of each wave
    float* r = red + ((tid >> 6) * 4 + jt) * 32;
#pragma unroll
    for (int bi = 0; bi < 8; ++bi) {
      float4 v4;
      v4.x = acc[bi][0]; v4.y = acc[bi][1];
      v4.z = acc[bi][2]; v4.w = acc[bi][3];
      *(float4*)(r + bi * 4) = v4;
    }
  }
}

__device__ __forceinline__ void domain_barrier(unsigned int* cptr,
                                               unsigned rnd) {
  __threadfence();
  __syncthreads();
  if (threadIdx.x == 0) {
    __hip_atomic_fetch_add(cptr, 1u, __ATOMIC_RELEASE, __HIP_MEMORY_SCOPE_AGENT);
    while (__hip_atomic_load(cptr, __ATOMIC_ACQUIRE, __HIP_MEMORY_SCOPE_AGENT) <
           32u * rnd)
      __builtin_amdgcn_s_sleep(1);
  }
  __syncthreads();
  __threadfence();   // reader-side: drop stale cached h before next staging
}

__global__ __launch_bounds__(512) void rnn_kernel(
    const float* pre0,                 // aliases d_out output region
    const float* __restrict__ h_init,  // (2,B,H)
    const float* __restrict__ Whh0, const float* __restrict__ Wih1,
    const float* __restrict__ b1, const float* __restrict__ Whh1,
    float* out,                        // d_out
    float* __restrict__ h0g, float* __restrict__ h1g,
    unsigned int* __restrict__ ctr) {
  extern __shared__ float sm[];
  float* W0s  = sm;            // [16][512] Whh0 slice
  float* W1s  = sm + 8192;     // Wih1 slice
  float* W2s  = sm + 16384;    // Whh1 slice
  float* h0s  = sm + 24576;    // [8][512]  h0(t-1)
  float* h1s  = sm + 28672;    // [8][512]  h1(t-2)
  float* red0 = sm + 32768;    // [8 waves][4 jt][32]
  float* red1 = sm + 33792;    // [8 waves][4 jt][32]   total 34816 f = 139264 B

  const int tid = threadIdx.x;
  const int blk = blockIdx.x;
  const int bg = blk & 7, jg = blk >> 3;
  const int b0i = bg * 8;
  const int j0 = jg * 16;
  unsigned int* cptr = ctr + bg * 32;

  // ---- stage weight slices into LDS (held for whole kernel) ----
  {
    const int row = tid >> 5, c = tid & 31;
    const float* w0r = Whh0 + (size_t)(j0 + row) * HH;
    const float* w1r = Wih1 + (size_t)(j0 + row) * HH;
    const float* w2r = Whh1 + (size_t)(j0 + row) * HH;
#pragma unroll
    for (int q = 0; q < 4; ++q) {
      const int ck = (c + q * 32) * 4;
      *(float4*)&W0s[row * 512 + ck] = *(const float4*)(w0r + ck);
      *(float4*)&W1s[row * 512 + ck] = *(const float4*)(w1r + ck);
      *(float4*)&W2s[row * 512 + ck] = *(const float4*)(w2r + ck);
    }
  }

  // ---- init ping-pong state (parity 1): h0g[1]=h_init[0], h1g[1]=h_init[1] --
  if (tid < 128) {
    const int jt2 = tid >> 5, slot = tid & 31;
    const int bi = slot >> 2, jj = slot & 3;
    const int b = b0i + bi, j = j0 + jt2 * 4 + jj;
    h0g[BH + b * HH + j] = h_init[b * HH + j];
    h1g[BH + b * HH + j] = h_init[BH + b * HH + j];
  }
  unsigned rnd = 1;
  domain_barrier(cptr, rnd); ++rnd;

  const int jt = tid & 3;
  const int kb = (tid >> 2) * 4;   // 128 k-slices of 4

  for (int t = 0; t <= SS; ++t) {
    // ---- stage h vectors: h0s <- h0(t-1), h1s <- h1(t-2) ----
    {
      const float* s0 = h0g + (size_t)((t + 1) & 1) * BH + b0i * HH;
      const float* s1 = h1g + (size_t)(t & 1) * BH + b0i * HH;
#pragma unroll
      for (int r = 0; r < 2; ++r) {
        const int idx = r * 512 + tid;
        const int b = idx >> 7, ck = (idx & 127) * 4;
        *(float4*)&h0s[b * 512 + ck] = *(const float4*)(s0 + b * HH + ck);
        *(float4*)&h1s[b * 512 + ck] = *(const float4*)(s1 + b * HH + ck);
      }
    }
    __syncthreads();

    // ---- all three matvecs from iter-start state ----
    float acc0[8][4] = {};
    float acc1[8][4] = {};
    if (t < SS) {
      mat_acc4(W0s, h0s, jt, kb, acc0);              // h0(t-1) @ Whh0^T
    }
    if (t > 0) {
      mat_acc4(W1s, h0s, jt, kb, acc1);              // h0(t-1) @ Wih1^T
      mat_acc4(W2s, h1s, jt, kb, acc1);              // h1(t-2) @ Whh1^T
    }

    // ---- interleaved butterfly reduce over the 16 k-subgroups in each wave --
#pragma unroll
    for (int off = 4; off <= 32; off <<= 1) {
#pragma unroll
      for (int bi = 0; bi < 8; ++bi)
#pragma unroll
        for (int jj = 0; jj < 4; ++jj) {
          acc0[bi][jj] += __shfl_xor(acc0[bi][jj], off, 64);
          acc1[bi][jj] += __shfl_xor(acc1[bi][jj], off, 64);
        }
    }
    store_partial(acc0, red0, tid, jt);
    store_partial(acc1, red1, tid, jt);
    __syncthreads();

    // ---- epilogue: cross-wave sum, bias/pre0, tanh, publish ----
    if (tid < 256) {
      const int lay = tid >> 7;                 // 0: layer0 h0(t), 1: layer1 h1(t-1)
      const int jt2 = (tid >> 5) & 3, slot = tid & 31;
      const float* rl = lay ? red1 : red0;
      float v = 0.f;
#pragma unroll
      for (int w = 0; w < 8; ++w) v += rl[(w * 4 + jt2) * 32 + slot];
      const int bi = slot >> 2, jj = slot & 3;
      const int b = b0i + bi, j = j0 + jt2 * 4 + jj;
      if (lay == 0) {
        if (t < SS) {
          v += pre0[((size_t)b * SS + t) * HH + j];
          v = tanhf(v);
          h0g[(size_t)(t & 1) * BH + b * HH + j] = v;
          if (t == SS - 1) out[HN_OFF + b * HH + j] = v;       // h_n[0]
        }
      } else {
        if (t > 0) {
          const int tm = t - 1;
          v += b1[j];
          v = tanhf(v);
          out[((size_t)b * SS + tm) * HH + j] = v;             // output[b][tm][j]
          h1g[(size_t)(tm & 1) * BH + b * HH + j] = v;
          if (tm == SS - 1) out[HN_OFF + BH + b * HH + j] = v; // h_n[1]
        }
      }
    }
    domain_barrier(cptr, rnd); ++rnd;
  }
}

// ============================================================================
extern "C" void kernel_launch(void* const* d_in, const int* in_sizes, int n_in,
                              void* d_out, int out_size, void* d_ws,
                              size_t ws_size, hipStream_t stream) {
  (void)in_sizes; (void)n_in; (void)out_size; (void)ws_size;
  const float* x    = (const float*)d_in[0];
  const float* h_in = (const float*)d_in[1];
  const float* Wih0 = (const float*)d_in[2];
  const float* b0   = (const float*)d_in[3];
  const float* Whh0 = (const float*)d_in[4];
  const float* Wih1 = (const float*)d_in[5];
  const float* b1   = (const float*)d_in[6];
  const float* Whh1 = (const float*)d_in[7];
  float* out = (float*)d_out;

  // workspace: h ping-pong + barrier counters (~0.5 MB)
  float* h0g = (float*)d_ws;              // [2][B][H]
  float* h1g = h0g + 2 * BH;              // [2][B][H]
  unsigned int* ctr = (unsigned int*)(h1g + 2 * BH);   // 8 domains, 128B apart

  hipMemsetAsync(ctr, 0, 8 * 32 * sizeof(unsigned int), stream);

  // Phase A: input projection for all timesteps (into d_out output region)
  pregemm_kernel<<<dim3(8, SS), dim3(256), 0, stream>>>(x, Wih0, b0, out);

  // Phase B: persistent recurrent kernel
  constexpr unsigned kLds = 34816u * 4u;   // 139264 B (< 160 KiB/CU)
  hipFuncSetAttribute(reinterpret_cast<const void*>(rnn_kernel),
                      hipFuncAttributeMaxDynamicSharedMemorySize, (int)kLds);
  const float* pre0c = out;
  void* args[] = {(void*)&pre0c, (void*)&h_in, (void*)&Whh0, (void*)&Wih1,
                  (void*)&b1,    (void*)&Whh1, (void*)&out,  (void*)&h0g,
                  (void*)&h1g,   (void*)&ctr};
  hipLaunchCooperativeKernel(reinterpret_cast<const void*>(rnn_kernel),
                             dim3(256), dim3(512), args, kLds, stream);
}

// Round 3
// 6782.685 us; speedup vs baseline: 5.9040x; 5.9040x over previous
//
#include <hip/hip_runtime.h>
#include <cstddef>

#define BB 64
#define SS 512
#define HH 512
#define BH (BB * HH)                     // 32768 floats
#define HN_OFF ((size_t)BB * SS * HH)    // start of h_n in d_out
#define WST 516                          // LDS W row stride (bank de-conflict)

// ============================================================================
// Kernel 1: pre0[b][t][j] = sum_i x[b,t,i] * Wih0[j,i] + b0[j]
// pre0 lives in the OUTPUT region of d_out (safe: rnn reads pre0[b][t] at
// iter t and overwrites out[b][t] at iter t+1, barrier-separated).
// ============================================================================
__global__ __launch_bounds__(256) void pregemm_kernel(
    const float* __restrict__ x, const float* __restrict__ Wih0,
    const float* __restrict__ b0, float* __restrict__ pre0) {
  __shared__ float xs[32][68];   // [k][b], padded
  __shared__ float ws[32][68];   // [k][j], padded
  const int t   = blockIdx.y;
  const int jb  = blockIdx.x * 64;
  const int tid = threadIdx.x;
  const int tx = tid & 15, ty = tid >> 4;       // compute mapping: 4b x 4j tile
  const int lrow = tid >> 2, kc = tid & 3;      // staging mapping

  float acc[4][4] = {{0.f, 0.f, 0.f, 0.f}, {0.f, 0.f, 0.f, 0.f},
                     {0.f, 0.f, 0.f, 0.f}, {0.f, 0.f, 0.f, 0.f}};

  const float* xrow = x + ((size_t)lrow * SS + t) * HH;       // b = lrow
  const float* wrow = Wih0 + (size_t)(jb + lrow) * HH;        // j = jb+lrow

  for (int k0 = 0; k0 < HH; k0 += 32) {
    float4 xa = *(const float4*)(xrow + k0 + kc * 4);
    float4 xb = *(const float4*)(xrow + k0 + (kc + 4) * 4);
    float4 wa = *(const float4*)(wrow + k0 + kc * 4);
    float4 wb = *(const float4*)(wrow + k0 + (kc + 4) * 4);
    __syncthreads();   // previous compute done before overwriting LDS
    xs[kc * 4 + 0][lrow] = xa.x; xs[kc * 4 + 1][lrow] = xa.y;
    xs[kc * 4 + 2][lrow] = xa.z; xs[kc * 4 + 3][lrow] = xa.w;
    xs[(kc + 4) * 4 + 0][lrow] = xb.x; xs[(kc + 4) * 4 + 1][lrow] = xb.y;
    xs[(kc + 4) * 4 + 2][lrow] = xb.z; xs[(kc + 4) * 4 + 3][lrow] = xb.w;
    ws[kc * 4 + 0][lrow] = wa.x; ws[kc * 4 + 1][lrow] = wa.y;
    ws[kc * 4 + 2][lrow] = wa.z; ws[kc * 4 + 3][lrow] = wa.w;
    ws[(kc + 4) * 4 + 0][lrow] = wb.x; ws[(kc + 4) * 4 + 1][lrow] = wb.y;
    ws[(kc + 4) * 4 + 2][lrow] = wb.z; ws[(kc + 4) * 4 + 3][lrow] = wb.w;
    __syncthreads();
#pragma unroll
    for (int kk = 0; kk < 32; ++kk) {
      float4 av = *(const float4*)&xs[kk][tx * 4];
      float4 bv = *(const float4*)&ws[kk][ty * 4];
      float aa[4] = {av.x, av.y, av.z, av.w};
      float bb4[4] = {bv.x, bv.y, bv.z, bv.w};
#pragma unroll
      for (int p = 0; p < 4; ++p)
#pragma unroll
        for (int q = 0; q < 4; ++q) acc[p][q] += aa[p] * bb4[q];
    }
  }
  float4 bias = *(const float4*)(b0 + jb + ty * 4);
  float bb4[4] = {bias.x, bias.y, bias.z, bias.w};
#pragma unroll
  for (int p = 0; p < 4; ++p) {
    float4 o;
    o.x = acc[p][0] + bb4[0]; o.y = acc[p][1] + bb4[1];
    o.z = acc[p][2] + bb4[2]; o.w = acc[p][3] + bb4[3];
    *(float4*)(pre0 + ((size_t)(tx * 4 + p) * SS + t) * HH + jb + ty * 4) = o;
  }
}

// ============================================================================
// Kernel 2: persistent recurrent kernel, 256 WGs x 512 thr.
// WG (bg = blk&7, jg = blk>>3) owns batches bg*8..+8, outputs j = jg*16..+16.
// Weights (3 x 16 x 512, padded stride 516) stay in LDS for the whole kernel.
// ALL cross-WG data (h0g, h1g, ctr) moves via relaxed agent-scope atomics
// (single sc0/sc1 coherent instructions, no cache flushes).  One 32-WG
// counting barrier per step; layer1 lags one step.
// ============================================================================
__device__ __forceinline__ void mat_acc4(const float* __restrict__ W,
                                         const float* __restrict__ h,
                                         int jt, int kb, float acc[8][4]) {
  float4 wv[4];
#pragma unroll
  for (int jj = 0; jj < 4; ++jj)
    wv[jj] = *(const float4*)&W[(jt * 4 + jj) * WST + kb];
#pragma unroll
  for (int bi = 0; bi < 8; ++bi) {
    float4 hv = *(const float4*)&h[bi * 512 + kb];
#pragma unroll
    for (int jj = 0; jj < 4; ++jj)
      acc[bi][jj] += hv.x * wv[jj].x + hv.y * wv[jj].y +
                     hv.z * wv[jj].z + hv.w * wv[jj].w;
  }
}

__device__ __forceinline__ void store_partial(float acc[8][4], float* red,
                                              int tid, int jt) {
  if (((tid >> 2) & 15) == 0) {          // lanes 0..3 of each wave
    float* r = red + ((tid >> 6) * 4 + jt) * 32;
#pragma unroll
    for (int bi = 0; bi < 8; ++bi) {
      float4 v4;
      v4.x = acc[bi][0]; v4.y = acc[bi][1];
      v4.z = acc[bi][2]; v4.w = acc[bi][3];
      *(float4*)(r + bi * 4) = v4;
    }
  }
}

// Counting barrier over the 32 WGs of one batch-group domain.
// __syncthreads() drains vmcnt(0), so all sc1 stores are at the coherence
// point before the counter bump; consumers read h with sc1 loads, so no
// cache-maintenance instructions are needed anywhere.
__device__ __forceinline__ void domain_barrier(unsigned int* cptr,
                                               unsigned target) {
  __syncthreads();
  if (threadIdx.x == 0) {
    __hip_atomic_fetch_add(cptr, 1u, __ATOMIC_RELAXED,
                           __HIP_MEMORY_SCOPE_AGENT);
    while (__hip_atomic_load(cptr, __ATOMIC_RELAXED,
                             __HIP_MEMORY_SCOPE_AGENT) < target)
      __builtin_amdgcn_s_sleep(2);
  }
  __syncthreads();
}

__global__ __launch_bounds__(512) void rnn_kernel(
    const float* pre0,                 // aliases d_out output region
    const float* __restrict__ h_init,  // (2,B,H)
    const float* __restrict__ Whh0, const float* __restrict__ Wih1,
    const float* __restrict__ b1, const float* __restrict__ Whh1,
    float* out,                        // d_out
    float* h0g, float* h1g,            // coherent ping-pong state
    unsigned int* ctr) {
  extern __shared__ float sm[];
  float* W0s  = sm;                  // [16][WST] Whh0 slice
  float* W1s  = sm + 16 * WST;       // Wih1 slice
  float* W2s  = sm + 32 * WST;       // Whh1 slice
  float* h0s  = sm + 48 * WST;       // [8][512]  h0(t-1)
  float* h1s  = sm + 48 * WST + 4096;  // [8][512]  h1(t-2)
  float* red0 = sm + 48 * WST + 8192;  // [8 waves][4 jt][32]
  float* red1 = sm + 48 * WST + 9216;  // [8 waves][4 jt][32]

  const int tid = threadIdx.x;
  const int blk = blockIdx.x;
  const int bg = blk & 7, jg = blk >> 3;
  const int b0i = bg * 8;
  const int j0 = jg * 16;
  unsigned int* cptr = ctr + bg * 32;

  // ---- stage weight slices into LDS (held for whole kernel) ----
  {
    const int row = tid >> 5, c = tid & 31;
    const float* w0r = Whh0 + (size_t)(j0 + row) * HH;
    const float* w1r = Wih1 + (size_t)(j0 + row) * HH;
    const float* w2r = Whh1 + (size_t)(j0 + row) * HH;
#pragma unroll
    for (int q = 0; q < 4; ++q) {
      const int ck = (c + q * 32) * 4;
      *(float4*)&W0s[row * WST + ck] = *(const float4*)(w0r + ck);
      *(float4*)&W1s[row * WST + ck] = *(const float4*)(w1r + ck);
      *(float4*)&W2s[row * WST + ck] = *(const float4*)(w2r + ck);
    }
  }

  // ---- init ping-pong state (parity 1) via coherent stores ----
  if (tid < 128) {
    const int jt2 = tid >> 5, slot = tid & 31;
    const int bi = slot >> 2, jj = slot & 3;
    const int b = b0i + bi, j = j0 + jt2 * 4 + jj;
    __hip_atomic_store(&h0g[BH + b * HH + j], h_init[b * HH + j],
                       __ATOMIC_RELAXED, __HIP_MEMORY_SCOPE_AGENT);
    __hip_atomic_store(&h1g[BH + b * HH + j], h_init[BH + b * HH + j],
                       __ATOMIC_RELAXED, __HIP_MEMORY_SCOPE_AGENT);
  }
  unsigned rnd = 1;
  domain_barrier(cptr, 32u * rnd); ++rnd;

  const int jt = tid & 3;
  const int kb = (tid >> 2) * 4;   // 128 k-slices of 4

  for (int t = 0; t <= SS; ++t) {
    // ---- stage h vectors (coherent loads): h0s <- h0(t-1), h1s <- h1(t-2) --
    {
      float* s0 = h0g + (size_t)((t + 1) & 1) * BH + (size_t)b0i * HH;
      float* s1 = h1g + (size_t)(t & 1) * BH + (size_t)b0i * HH;
#pragma unroll
      for (int q = 0; q < 8; ++q) {
        h0s[q * 512 + tid] = __hip_atomic_load(
            s0 + q * 512 + tid, __ATOMIC_RELAXED, __HIP_MEMORY_SCOPE_AGENT);
        h1s[q * 512 + tid] = __hip_atomic_load(
            s1 + q * 512 + tid, __ATOMIC_RELAXED, __HIP_MEMORY_SCOPE_AGENT);
      }
    }
    __syncthreads();

    // ---- all three matvecs from iter-start state ----
    float acc0[8][4] = {};
    float acc1[8][4] = {};
    if (t < SS) {
      mat_acc4(W0s, h0s, jt, kb, acc0);              // h0(t-1) @ Whh0^T
    }
    if (t > 0) {
      mat_acc4(W1s, h0s, jt, kb, acc1);              // h0(t-1) @ Wih1^T
      mat_acc4(W2s, h1s, jt, kb, acc1);              // h1(t-2) @ Whh1^T
    }

    // ---- interleaved butterfly reduce over 16 k-subgroups in each wave ----
#pragma unroll
    for (int off = 4; off <= 32; off <<= 1) {
#pragma unroll
      for (int bi = 0; bi < 8; ++bi)
#pragma unroll
        for (int jj = 0; jj < 4; ++jj) {
          acc0[bi][jj] += __shfl_xor(acc0[bi][jj], off, 64);
          acc1[bi][jj] += __shfl_xor(acc1[bi][jj], off, 64);
        }
    }
    store_partial(acc0, red0, tid, jt);
    store_partial(acc1, red1, tid, jt);
    __syncthreads();

    // ---- epilogue: cross-wave sum, bias/pre0, tanh, publish ----
    if (tid < 256) {
      const int lay = tid >> 7;            // 0: layer0 h0(t), 1: layer1 h1(t-1)
      const int jt2 = (tid >> 5) & 3, slot = tid & 31;
      const float* rl = lay ? red1 : red0;
      float v = 0.f;
#pragma unroll
      for (int w = 0; w < 8; ++w) v += rl[(w * 4 + jt2) * 32 + slot];
      const int bi = slot >> 2, jj = slot & 3;
      const int b = b0i + bi, j = j0 + jt2 * 4 + jj;
      if (lay == 0) {
        if (t < SS) {
          v += pre0[((size_t)b * SS + t) * HH + j];
          v = tanhf(v);
          __hip_atomic_store(&h0g[(size_t)(t & 1) * BH + b * HH + j], v,
                             __ATOMIC_RELAXED, __HIP_MEMORY_SCOPE_AGENT);
          if (t == SS - 1) out[HN_OFF + b * HH + j] = v;       // h_n[0]
        }
      } else {
        if (t > 0) {
          const int tm = t - 1;
          v += b1[j];
          v = tanhf(v);
          out[((size_t)b * SS + tm) * HH + j] = v;             // output[b][tm]
          __hip_atomic_store(&h1g[(size_t)(tm & 1) * BH + b * HH + j], v,
                             __ATOMIC_RELAXED, __HIP_MEMORY_SCOPE_AGENT);
          if (tm == SS - 1) out[HN_OFF + BH + b * HH + j] = v; // h_n[1]
        }
      }
    }
    domain_barrier(cptr, 32u * rnd); ++rnd;
  }
}

// ============================================================================
extern "C" void kernel_launch(void* const* d_in, const int* in_sizes, int n_in,
                              void* d_out, int out_size, void* d_ws,
                              size_t ws_size, hipStream_t stream) {
  (void)in_sizes; (void)n_in; (void)out_size; (void)ws_size;
  const float* x    = (const float*)d_in[0];
  const float* h_in = (const float*)d_in[1];
  const float* Wih0 = (const float*)d_in[2];
  const float* b0   = (const float*)d_in[3];
  const float* Whh0 = (const float*)d_in[4];
  const float* Wih1 = (const float*)d_in[5];
  const float* b1   = (const float*)d_in[6];
  const float* Whh1 = (const float*)d_in[7];
  float* out = (float*)d_out;

  // workspace: h ping-pong + barrier counters (~0.5 MB)
  float* h0g = (float*)d_ws;              // [2][B][H]
  float* h1g = h0g + 2 * BH;              // [2][B][H]
  unsigned int* ctr = (unsigned int*)(h1g + 2 * BH);   // 8 domains, 128B apart

  hipMemsetAsync(ctr, 0, 8 * 32 * sizeof(unsigned int), stream);

  // Phase A: input projection for all timesteps (into d_out output region)
  pregemm_kernel<<<dim3(8, SS), dim3(256), 0, stream>>>(x, Wih0, b0, out);

  // Phase B: persistent recurrent kernel
  constexpr unsigned kLds = (48 * WST + 10240) * 4u;   // 140032 B < 160 KiB
  hipFuncSetAttribute(reinterpret_cast<const void*>(rnn_kernel),
                      hipFuncAttributeMaxDynamicSharedMemorySize, (int)kLds);
  const float* pre0c = out;
  void* args[] = {(void*)&pre0c, (void*)&h_in, (void*)&Whh0, (void*)&Wih1,
                  (void*)&b1,    (void*)&Whh1, (void*)&out,  (void*)&h0g,
                  (void*)&h1g,   (void*)&ctr};
  hipLaunchCooperativeKernel(reinterpret_cast<const void*>(rnn_kernel),
                             dim3(256), dim3(512), args, kLds, stream);
}

// Round 4
// 3224.895 us; speedup vs baseline: 12.4174x; 2.1032x over previous
//
#include <hip/hip_runtime.h>
#include <cstddef>

#define BB 64
#define SS 512
#define HH 512
#define BH (BB * HH)                     // 32768 floats
#define HN_OFF ((size_t)BB * SS * HH)    // start of h_n in d_out
#define WST 516                          // LDS W row stride

// ============================================================================
// Kernel 1: pre0[b][t][j] = sum_i x[b,t,i] * Wih0[j,i] + b0[j]
// pre0 lives in the OUTPUT region of d_out (safe: rnn reads pre0[b][t] at
// iter t and overwrites out[b][t] at iter t+1, barrier-separated).
// ============================================================================
__global__ __launch_bounds__(256) void pregemm_kernel(
    const float* __restrict__ x, const float* __restrict__ Wih0,
    const float* __restrict__ b0, float* __restrict__ pre0) {
  __shared__ float xs[32][68];   // [k][b], padded
  __shared__ float ws[32][68];   // [k][j], padded
  const int t   = blockIdx.y;
  const int jb  = blockIdx.x * 64;
  const int tid = threadIdx.x;
  const int tx = tid & 15, ty = tid >> 4;       // compute mapping: 4b x 4j tile
  const int lrow = tid >> 2, kc = tid & 3;      // staging mapping

  float acc[4][4] = {{0.f, 0.f, 0.f, 0.f}, {0.f, 0.f, 0.f, 0.f},
                     {0.f, 0.f, 0.f, 0.f}, {0.f, 0.f, 0.f, 0.f}};

  const float* xrow = x + ((size_t)lrow * SS + t) * HH;       // b = lrow
  const float* wrow = Wih0 + (size_t)(jb + lrow) * HH;        // j = jb+lrow

  for (int k0 = 0; k0 < HH; k0 += 32) {
    float4 xa = *(const float4*)(xrow + k0 + kc * 4);
    float4 xb = *(const float4*)(xrow + k0 + (kc + 4) * 4);
    float4 wa = *(const float4*)(wrow + k0 + kc * 4);
    float4 wb = *(const float4*)(wrow + k0 + (kc + 4) * 4);
    __syncthreads();   // previous compute done before overwriting LDS
    xs[kc * 4 + 0][lrow] = xa.x; xs[kc * 4 + 1][lrow] = xa.y;
    xs[kc * 4 + 2][lrow] = xa.z; xs[kc * 4 + 3][lrow] = xa.w;
    xs[(kc + 4) * 4 + 0][lrow] = xb.x; xs[(kc + 4) * 4 + 1][lrow] = xb.y;
    xs[(kc + 4) * 4 + 2][lrow] = xb.z; xs[(kc + 4) * 4 + 3][lrow] = xb.w;
    ws[kc * 4 + 0][lrow] = wa.x; ws[kc * 4 + 1][lrow] = wa.y;
    ws[kc * 4 + 2][lrow] = wa.z; ws[kc * 4 + 3][lrow] = wa.w;
    ws[(kc + 4) * 4 + 0][lrow] = wb.x; ws[(kc + 4) * 4 + 1][lrow] = wb.y;
    ws[(kc + 4) * 4 + 2][lrow] = wb.z; ws[(kc + 4) * 4 + 3][lrow] = wb.w;
    __syncthreads();
#pragma unroll
    for (int kk = 0; kk < 32; ++kk) {
      float4 av = *(const float4*)&xs[kk][tx * 4];
      float4 bv = *(const float4*)&ws[kk][ty * 4];
      float aa[4] = {av.x, av.y, av.z, av.w};
      float bb4[4] = {bv.x, bv.y, bv.z, bv.w};
#pragma unroll
      for (int p = 0; p < 4; ++p)
#pragma unroll
        for (int q = 0; q < 4; ++q) acc[p][q] += aa[p] * bb4[q];
    }
  }
  float4 bias = *(const float4*)(b0 + jb + ty * 4);
  float bb4[4] = {bias.x, bias.y, bias.z, bias.w};
#pragma unroll
  for (int p = 0; p < 4; ++p) {
    float4 o;
    o.x = acc[p][0] + bb4[0]; o.y = acc[p][1] + bb4[1];
    o.z = acc[p][2] + bb4[2]; o.w = acc[p][3] + bb4[3];
    *(float4*)(pre0 + ((size_t)(tx * 4 + p) * SS + t) * HH + jb + ty * 4) = o;
  }
}

// ============================================================================
// Wave-wide reduce over lane bits 2..5 (the 16 k-subgroups):
//   rounds 4,8: DPP row_ror fused adds (VALU, rows of 16)
//   round 16:   shfl_xor (1 LDS swizzle)
//   round 32:   permlane32_swap (VALU)
// ============================================================================
__device__ __forceinline__ float wave_red64(float x) {
  int tdpp;
  tdpp = __builtin_amdgcn_update_dpp(0, __builtin_bit_cast(int, x),
                                     0x124, 0xF, 0xF, true);   // row_ror:4
  x += __builtin_bit_cast(float, tdpp);
  tdpp = __builtin_amdgcn_update_dpp(0, __builtin_bit_cast(int, x),
                                     0x128, 0xF, 0xF, true);   // row_ror:8
  x += __builtin_bit_cast(float, tdpp);
  x += __shfl_xor(x, 16, 64);
  {
    unsigned a = __builtin_bit_cast(unsigned, x);
    auto r = __builtin_amdgcn_permlane32_swap(a, a, false, false);
    x = __builtin_bit_cast(float, (unsigned)r[0]) +
        __builtin_bit_cast(float, (unsigned)r[1]);
  }
  return x;
}

__device__ __forceinline__ void store_partial(float acc[8][4], float* red,
                                              int tid, int jt) {
  if (((tid >> 2) & 15) == 0) {          // lanes 0..3 of each wave
    float* r = red + ((tid >> 6) * 4 + jt) * 32;
#pragma unroll
    for (int bi = 0; bi < 8; ++bi) {
      float4 v4;
      v4.x = acc[bi][0]; v4.y = acc[bi][1];
      v4.z = acc[bi][2]; v4.w = acc[bi][3];
      *(float4*)(r + bi * 4) = v4;
    }
  }
}

// Counting barrier over the 32 WGs of one batch-group domain.  All
// cross-WG payloads move via sc0/sc1 coherent accesses; __syncthreads
// drains vmcnt so publishes are at the coherence point before the bump.
__device__ __forceinline__ void domain_barrier(unsigned int* cptr,
                                               unsigned target) {
  __syncthreads();
  if (threadIdx.x == 0) {
    __hip_atomic_fetch_add(cptr, 1u, __ATOMIC_RELAXED,
                           __HIP_MEMORY_SCOPE_AGENT);
    while (__hip_atomic_load(cptr, __ATOMIC_RELAXED,
                             __HIP_MEMORY_SCOPE_AGENT) < target)
      __builtin_amdgcn_s_sleep(1);
  }
  __syncthreads();
}

// ============================================================================
// Kernel 2: persistent recurrent kernel, 256 WGs x 512 thr.
// WG (bg=blk&7, jg=blk>>3) owns batches bg*8..+8, outputs j = jg*16..+16.
// Weights (3 x 16 x 512, stride 516) live in LDS for the whole kernel.
// One 32-WG counting barrier per step; layer1 lags one step.
// ============================================================================
__global__ __launch_bounds__(512, 2) void rnn_kernel(
    const float* pre0,                 // aliases d_out output region
    const float* __restrict__ h_init,  // (2,B,H)
    const float* __restrict__ Whh0, const float* __restrict__ Wih1,
    const float* __restrict__ b1, const float* __restrict__ Whh1,
    float* out,                        // d_out
    float* h0g, float* h1g,            // coherent ping-pong state
    unsigned int* ctr) {
  extern __shared__ float sm[];
  float* W0s  = sm;                    // [16][WST] Whh0 slice
  float* W1s  = sm + 16 * WST;         // Wih1 slice
  float* W2s  = sm + 32 * WST;         // Whh1 slice
  float* h0s  = sm + 48 * WST;         // [8][512]  h0(t-1)
  float* h1s  = sm + 48 * WST + 4096;  // [8][512]  h1(t-2)
  float* red0 = sm + 48 * WST + 8192;  // [8 waves][4 jt][32]
  float* red1 = sm + 48 * WST + 9216;  // [8 waves][4 jt][32]

  const int tid = threadIdx.x;
  const int blk = blockIdx.x;
  const int bg = blk & 7, jg = blk >> 3;
  const int b0i = bg * 8;
  const int j0 = jg * 16;
  unsigned int* cptr = ctr + bg * 32;

  // ---- stage weight slices into LDS (held for whole kernel) ----
  {
    const int row = tid >> 5, c = tid & 31;
    const float* w0r = Whh0 + (size_t)(j0 + row) * HH;
    const float* w1r = Wih1 + (size_t)(j0 + row) * HH;
    const float* w2r = Whh1 + (size_t)(j0 + row) * HH;
#pragma unroll
    for (int q = 0; q < 4; ++q) {
      const int ck = (c + q * 32) * 4;
      *(float4*)&W0s[row * WST + ck] = *(const float4*)(w0r + ck);
      *(float4*)&W1s[row * WST + ck] = *(const float4*)(w1r + ck);
      *(float4*)&W2s[row * WST + ck] = *(const float4*)(w2r + ck);
    }
  }

  // ---- epilogue thread mapping (tid<256): hoist invariants ----
  const int e_jt2 = (tid >> 5) & 3, e_slot = tid & 31;
  const int e_bi = e_slot >> 2, e_jj = e_slot & 3;
  const int e_b = b0i + e_bi, e_j = j0 + e_jt2 * 4 + e_jj;
  const float bias1 = b1[e_j];                        // loop-invariant

  // ---- init ping-pong state (parity 1) via coherent stores ----
  if (tid < 128) {
    __hip_atomic_store(&h0g[BH + e_b * HH + e_j], h_init[e_b * HH + e_j],
                       __ATOMIC_RELAXED, __HIP_MEMORY_SCOPE_AGENT);
    __hip_atomic_store(&h1g[BH + e_b * HH + e_j], h_init[BH + e_b * HH + e_j],
                       __ATOMIC_RELAXED, __HIP_MEMORY_SCOPE_AGENT);
  }
  unsigned rnd = 1;
  domain_barrier(cptr, 32u * rnd); ++rnd;

  const int jt = tid & 3;
  const int kb = (tid >> 2) * 4;   // 128 k-slices of 4

  for (int t = 0; t <= SS; ++t) {
    // ---- prefetch pre0[:,t] for epilogue (plain cached, latency hidden) ----
    float pre_t = 0.f;
    if (t < SS && tid < 128)
      pre_t = pre0[((size_t)e_b * SS + t) * HH + e_j];

    // ---- stage h (coherent dwordx4): h0s <- h0(t-1), h1s <- h1(t-2) ----
    {
      const float* s0 = h0g + (size_t)((t + 1) & 1) * BH + (size_t)b0i * HH;
      const float* s1 = h1g + (size_t)(t & 1) * BH + (size_t)b0i * HH;
      float4 a0, a1, c0, c1;
      asm volatile(
          "global_load_dwordx4 %0, %4, off sc0 sc1\n\t"
          "global_load_dwordx4 %1, %5, off sc0 sc1\n\t"
          "global_load_dwordx4 %2, %6, off sc0 sc1\n\t"
          "global_load_dwordx4 %3, %7, off sc0 sc1"
          : "=v"(a0), "=v"(a1), "=v"(c0), "=v"(c1)
          : "v"(s0 + tid * 4), "v"(s0 + 2048 + tid * 4),
            "v"(s1 + tid * 4), "v"(s1 + 2048 + tid * 4));
      asm volatile("s_waitcnt vmcnt(0)" ::: "memory");
      __builtin_amdgcn_sched_barrier(0);
      *(float4*)&h0s[tid * 4] = a0;
      *(float4*)&h0s[2048 + tid * 4] = a1;
      *(float4*)&h1s[tid * 4] = c0;
      *(float4*)&h1s[2048 + tid * 4] = c1;
    }
    __syncthreads();

    // ---- fused 3-matvec compute (W/h from LDS, CSE'd h loads) ----
    float acc0[8][4] = {};
    float acc1[8][4] = {};
    {
      float4 w0v[4], w1v[4], w2v[4];
#pragma unroll
      for (int jj = 0; jj < 4; ++jj) {
        w0v[jj] = *(const float4*)&W0s[(jt * 4 + jj) * WST + kb];
        w1v[jj] = *(const float4*)&W1s[(jt * 4 + jj) * WST + kb];
        w2v[jj] = *(const float4*)&W2s[(jt * 4 + jj) * WST + kb];
      }
#pragma unroll
      for (int bi = 0; bi < 8; ++bi) {
        float4 h0v = *(const float4*)&h0s[bi * 512 + kb];
        float4 h1v = *(const float4*)&h1s[bi * 512 + kb];
#pragma unroll
        for (int jj = 0; jj < 4; ++jj) {
          acc0[bi][jj] += h0v.x * w0v[jj].x + h0v.y * w0v[jj].y +
                          h0v.z * w0v[jj].z + h0v.w * w0v[jj].w;
          acc1[bi][jj] += h0v.x * w1v[jj].x + h0v.y * w1v[jj].y +
                          h0v.z * w1v[jj].z + h0v.w * w1v[jj].w +
                          h1v.x * w2v[jj].x + h1v.y * w2v[jj].y +
                          h1v.z * w2v[jj].z + h1v.w * w2v[jj].w;
        }
      }
    }

    // ---- wave reduce (VALU DPP/permlane, 1 LDS swizzle per value) ----
#pragma unroll
    for (int bi = 0; bi < 8; ++bi)
#pragma unroll
      for (int jj = 0; jj < 4; ++jj) {
        acc0[bi][jj] = wave_red64(acc0[bi][jj]);
        acc1[bi][jj] = wave_red64(acc1[bi][jj]);
      }
    store_partial(acc0, red0, tid, jt);
    store_partial(acc1, red1, tid, jt);
    __syncthreads();

    // ---- epilogue: cross-wave sum, bias/pre0, tanh, publish ----
    if (tid < 256) {
      const int lay = tid >> 7;            // 0: layer0 h0(t), 1: layer1 h1(t-1)
      const float* rl = lay ? red1 : red0;
      float v = 0.f;
#pragma unroll
      for (int w = 0; w < 8; ++w) v += rl[(w * 4 + e_jt2) * 32 + e_slot];
      if (lay == 0) {
        if (t < SS) {
          v += pre_t;
          v = tanhf(v);
          __hip_atomic_store(&h0g[(size_t)(t & 1) * BH + e_b * HH + e_j], v,
                             __ATOMIC_RELAXED, __HIP_MEMORY_SCOPE_AGENT);
          if (t == SS - 1) out[HN_OFF + e_b * HH + e_j] = v;       // h_n[0]
        }
      } else {
        if (t > 0) {
          const int tm = t - 1;
          v += bias1;
          v = tanhf(v);
          out[((size_t)e_b * SS + tm) * HH + e_j] = v;             // output
          __hip_atomic_store(&h1g[(size_t)(tm & 1) * BH + e_b * HH + e_j], v,
                             __ATOMIC_RELAXED, __HIP_MEMORY_SCOPE_AGENT);
          if (tm == SS - 1) out[HN_OFF + BH + e_b * HH + e_j] = v; // h_n[1]
        }
      }
    }
    domain_barrier(cptr, 32u * rnd); ++rnd;
  }
}

// ============================================================================
extern "C" void kernel_launch(void* const* d_in, const int* in_sizes, int n_in,
                              void* d_out, int out_size, void* d_ws,
                              size_t ws_size, hipStream_t stream) {
  (void)in_sizes; (void)n_in; (void)out_size; (void)ws_size;
  const float* x    = (const float*)d_in[0];
  const float* h_in = (const float*)d_in[1];
  const float* Wih0 = (const float*)d_in[2];
  const float* b0   = (const float*)d_in[3];
  const float* Whh0 = (const float*)d_in[4];
  const float* Wih1 = (const float*)d_in[5];
  const float* b1   = (const float*)d_in[6];
  const float* Whh1 = (const float*)d_in[7];
  float* out = (float*)d_out;

  // workspace: h ping-pong + barrier counters (~0.5 MB)
  float* h0g = (float*)d_ws;              // [2][B][H]
  float* h1g = h0g + 2 * BH;              // [2][B][H]
  unsigned int* ctr = (unsigned int*)(h1g + 2 * BH);   // 8 domains, 128B apart

  hipMemsetAsync(ctr, 0, 8 * 32 * sizeof(unsigned int), stream);

  // Phase A: input projection for all timesteps (into d_out output region)
  pregemm_kernel<<<dim3(8, SS), dim3(256), 0, stream>>>(x, Wih0, b0, out);

  // Phase B: persistent recurrent kernel
  constexpr unsigned kLds = (48 * WST + 10240) * 4u;   // 140032 B < 160 KiB
  hipFuncSetAttribute(reinterpret_cast<const void*>(rnn_kernel),
                      hipFuncAttributeMaxDynamicSharedMemorySize, (int)kLds);
  const float* pre0c = out;
  void* args[] = {(void*)&pre0c, (void*)&h_in, (void*)&Whh0, (void*)&Wih1,
                  (void*)&b1,    (void*)&Whh1, (void*)&out,  (void*)&h0g,
                  (void*)&h1g,   (void*)&ctr};
  hipLaunchCooperativeKernel(reinterpret_cast<const void*>(rnn_kernel),
                             dim3(256), dim3(512), args, kLds, stream);
}